// Round 20
// baseline (372.971 us; speedup 1.0000x reference)
//
#include <hip/hip_runtime.h>
#include <hip/hip_bf16.h>
#include <math.h>

#define SEQ   2048
#define EMBD  2048
#define NH    16
#define NKV   4
#define HD    128
#define NQKV  3072
#define NUNITS 608        // 512 strip-pair units + 96 second-chunks of split units

typedef __attribute__((ext_vector_type(8))) short short8;
typedef __attribute__((ext_vector_type(4))) short short4v;
typedef __attribute__((ext_vector_type(4))) float floatx4;

static __device__ __forceinline__ short f2bf(float f) {
    union { float f; unsigned u; } cv; cv.f = f;
    unsigned u = cv.u;
    u += 0x7FFF + ((u >> 16) & 1);   // round-to-nearest-even
    return (short)(u >> 16);
}

// async global->LDS, 16B per lane. LDS dest = wave-uniform base + lane*16.
#define GL16(gsrc, ldst)                                                        \
    __builtin_amdgcn_global_load_lds(                                           \
        (const __attribute__((address_space(1))) void*)(gsrc),                  \
        (__attribute__((address_space(3))) void*)(ldst), 16, 0, 0)

// ALiBi window in 64-tiles: truncated mass beyond W is < ~0.2% relative
static __device__ __forceinline__ int alibi_window(float slope2) {
    return (int)ceilf((32.0f / slope2 + 63.0f) * (1.0f / 64.0f));
}

// ---------------- compile-time cost-sorted unit table -------------------------
// Unit order is a pure function of shape; only scheduling (not correctness)
// depends on it: kernel derives its own bounds from (c,b,h,p). W_TAB mirrors
// alibi_window(slope2(h)) for h=0..15.
struct QTab { int v[NUNITS]; };
static constexpr int W_TAB[16] = {2,2,2,3,3,4,5,7,9,13,17,24,33,46,64,90};
static constexpr QTab make_qtab() {
    QTab t{};
    int cost[NUNITS] = {}, enc[NUNITS] = {};
    for (int i = 0; i < NUNITS; ++i) {
        int b, h, p, c;
        if (i < 512) { b = i >> 8; h = (i >> 4) & 15; p = i & 15; c = 0; }
        else { int j = i - 512; b = j / 48; int r2 = j % 48; h = 10 + r2 / 8; p = 8 + r2 % 8; c = 1; }
        int W = W_TAB[h];
        int L = (W + 1 < 2 * p + 2) ? (W + 1) : (2 * p + 2);
        int n0 = (L + 1) >> 1;
        bool split = (h >= 10) && (p >= 8);
        cost[i] = split ? (c == 0 ? n0 : L - n0) : L;
        enc[i] = (c << 9) | (b << 8) | (h << 4) | p;
    }
    int idx = 0;
    for (int cval = 32; cval >= 1; --cval)          // counting sort, cost desc
        for (int i = NUNITS - 1; i >= 0; --i)       // larger i first (matches old key)
            if (cost[i] == cval) t.v[idx++] = enc[i];
    return t;
}
static __constant__ QTab d_qt = make_qtab();

// ---------------- fused fp32 -> bf16 convert (all 5 tensors, one launch) ------
__global__ void cvt_all(const float* __restrict__ x,  const float* __restrict__ qw,
                        const float* __restrict__ kw, const float* __restrict__ vw,
                        const float* __restrict__ ow,
                        short* __restrict__ xb, short* __restrict__ wall,
                        short* __restrict__ owb) {
    int i = blockIdx.x * blockDim.x + threadIdx.x;   // quad index, < 4718592
    const float* src; short* dst; int off;
    if (i < 2097152)      { src = x;  dst = xb;             off = i; }
    else if (i < 3145728) { src = qw; dst = wall;           off = i - 2097152; }
    else if (i < 3407872) { src = kw; dst = wall + 4194304; off = i - 3145728; }
    else if (i < 3670016) { src = vw; dst = wall + 5242880; off = i - 3407872; }
    else                  { src = ow; dst = owb;            off = i - 3670016; }
    float4 v = ((const float4*)src)[off];
    float a[4] = {v.x, v.y, v.z, v.w};
    short4v o;
#pragma unroll
    for (int j = 0; j < 4; ++j) {
        float f = a[j];
        f = isnan(f) ? 0.0f : fminf(fmaxf(f, -10000.0f), 10000.0f);
        o[j] = f2bf(f);
    }
    ((short4v*)dst)[off] = o;
}

// ---------------- bf16 GEMM: 128x128 tile, BK=64, swizzled LDS (R15) ----------
// global_load_lds staging with pre-XORed source (seg^(row&7) on 16B chunks);
// fragment ds_read_b128 XORs the same way -> 2-way (free) bank access.
// Single-buffered: cross-block TLP (4 blocks/CU at 32KB LDS) hides the drain.
// MODE 0: scatter epilogue -> Q (pre-scaled by scale*log2e), K, VT (bf16)
// MODE 1: plain fp32 store
template<int MODE>
__global__ __launch_bounds__(256) void gemm_bt(
    const short* __restrict__ A, const short* __restrict__ W,
    float* __restrict__ Cout, int M, int N, int K,
    short* __restrict__ qb, short* __restrict__ kb, short* __restrict__ vb)
{
    __shared__ __align__(16) short sA[128 * 64];
    __shared__ __align__(16) short sB[128 * 64];

    const int tid  = threadIdx.x;
    const int lane = tid & 63;
    const int wv   = tid >> 6;
    const int wr   = wv >> 1, wc = wv & 1;       // 2x2 wave grid, 64x64 each
    const int lr   = lane & 15, lg = lane >> 4;
    const int bn   = blockIdx.x, bm = blockIdx.y;

    // staging: 1024 chunks(16B) per matrix; wave w covers [w*256, w*256+256)
    const short* gA[4]; const short* gB[4];
    short* lA[4]; short* lB[4];
#pragma unroll
    for (int s = 0; s < 4; ++s) {
        int ck  = wv * 256 + s * 64 + lane;
        int row = ck >> 3, seg = ck & 7;         // 8x16B chunks per 64-short row
        int segSw = seg ^ (row & 7);             // pre-swizzled source column
        gA[s] = A + (size_t)(bm * 128 + row) * K + segSw * 8;
        gB[s] = W + (size_t)(bn * 128 + row) * K + segSw * 8;
        lA[s] = &sA[(wv * 256 + s * 64) * 8];    // linear dest
        lB[s] = &sB[(wv * 256 + s * 64) * 8];
    }

    floatx4 acc[4][4] = {};
    const int nkt = K / 64;
    for (int kt = 0; kt < nkt; ++kt) {
#pragma unroll
        for (int s = 0; s < 4; ++s) {
            GL16(gA[s] + kt * 64, lA[s]);
            GL16(gB[s] + kt * 64, lB[s]);
        }
        __syncthreads();

#pragma unroll
        for (int ks = 0; ks < 2; ++ks) {
            short8 af[4], bfr[4];
#pragma unroll
            for (int i = 0; i < 4; ++i) {
                int ra = wr * 64 + i * 16 + lr;
                int rb = wc * 64 + i * 16 + lr;
                af[i]  = *(const short8*)&sA[ra * 64 + (((ks * 4 + lg) ^ (ra & 7)) * 8)];
                bfr[i] = *(const short8*)&sB[rb * 64 + (((ks * 4 + lg) ^ (rb & 7)) * 8)];
            }
#pragma unroll
            for (int i = 0; i < 4; ++i)
#pragma unroll
                for (int j = 0; j < 4; ++j)
                    acc[i][j] = __builtin_amdgcn_mfma_f32_16x16x32_bf16(af[i], bfr[j], acc[i][j], 0, 0, 0);
        }
        __syncthreads();
    }

    const float QSCALE = 0.08838834764831845f * 1.44269504f;  // scale * log2e
#pragma unroll
    for (int i = 0; i < 4; ++i)
#pragma unroll
        for (int j = 0; j < 4; ++j)
#pragma unroll
            for (int r = 0; r < 4; ++r) {
                int gm = bm * 128 + wr * 64 + i * 16 + lg * 4 + r;
                int gn = bn * 128 + wc * 64 + j * 16 + lr;
                float v = acc[i][j][r];
                if (MODE == 0) {
                    int b = gm >> 11, t = gm & (SEQ - 1);
                    if (gn < 2048) {
                        int h = gn >> 7, d = gn & 127;
                        qb[(((size_t)(b * NH + h)) * SEQ + t) * HD + d] = f2bf(v * QSCALE);
                    } else if (gn < 2560) {
                        int hk = (gn - 2048) >> 7, d = gn & 127;
                        kb[(((size_t)(b * NKV + hk)) * SEQ + t) * HD + d] = f2bf(v);
                    } else {
                        int hv = (gn - 2560) >> 7, d = gn & 127;
                        vb[(((size_t)(b * NKV + hv)) * HD + d) * SEQ + t] = f2bf(v);
                    }
                } else {
                    Cout[(size_t)gm * N + gn] = v;
                }
            }
}

// ---------------- flash attention: 3 blocks/CU, single-buffered K+V -----------
// 768 persistent blocks (8 waves, 48KB LDS -> 3/CU = 24 waves/CU). K and V
// single-buffered: issue both at tile top, ONE drain barrier, compute (Plds
// wave-private, swizzled [8][16][64] -> no mid-tile barrier), end barrier.
// Exposed load latency is covered by the co-resident blocks (TLP). Queue +
// split units + combine identical to R19.
__global__ __launch_bounds__(512, 6) void attn_fwd(
    const short* __restrict__ Q, const short* __restrict__ Kg,
    const short* __restrict__ VT, short* __restrict__ Y,
    float* __restrict__ part, int* __restrict__ qcnt)
{
    __shared__ __align__(16) short sK[64 * 128];      // 16 KB, swizzled chunks
    __shared__ __align__(16) short sV[128 * 64];      // 16 KB, swizzled chunks
    __shared__ short Plds[8][16][64];                 // 16 KB, XOR-swizzled cols
    __shared__ int s_unit;

    const int tid  = threadIdx.x;
    const int wave = tid >> 6, lane = tid & 63;
    const int lr = lane & 15, lg = lane >> 4;

    int lOff[2];
#pragma unroll
    for (int j = 0; j < 2; ++j)
        lOff[j] = (wave * 128 + j * 64 + lane) * 8;   // lane-linear, 16B chunks

    for (;;) {
        if (tid == 0) {
            int r = atomicAdd(qcnt, 1);
            s_unit = (r < NUNITS) ? d_qt.v[r] : -1;
        }
        __syncthreads();
        const int enc = s_unit;
        __syncthreads();
        if (enc < 0) break;

        const int c = (enc >> 9) & 1, b = (enc >> 8) & 1;
        const int h = (enc >> 4) & 15, p = enc & 15;
        const int hkv = h >> 2;               // repeat_interleave: head h -> kv h/4
        const int qgw = 2 * p + (wave < 4 ? 1 : 0);   // this wave's strip

        const short* Qb = Q  +  ((size_t)(b * NH  + h  )) * SEQ * HD;
        const short* Kp = Kg +  ((size_t)(b * NKV + hkv)) * SEQ * HD;
        const short* Vp = VT +  ((size_t)(b * NKV + hkv)) * HD * SEQ;

        const float slope2 = exp2f(-0.5f * (float)(h + 1)) * 1.44269504f;
        const int W = alibi_window(slope2);
        const int thi = 2 * p + 1;
        const int L = min(W + 1, 2 * p + 2);
        const bool split = (h >= 10) && (p >= 8);
        const int n0 = (L + 1) >> 1;
        int t1, t0;
        if (!split)      { t1 = thi;      t0 = thi - L + 1; }
        else if (c == 0) { t1 = thi;      t0 = thi - n0 + 1; }
        else             { t1 = thi - n0; t0 = thi - L + 1; }

        const short* gK[2]; const short* gV[2];
#pragma unroll
        for (int j = 0; j < 2; ++j) {
            int ck = wave * 128 + j * 64 + lane;
            int krow = ck >> 4, kseg = ck & 15;
            gK[j] = Kp + (size_t)krow * HD + (kseg ^ (krow & 7)) * 8;   // pre-swz src
            int vrow = ck >> 3, vseg = ck & 7;
            gV[j] = Vp + (size_t)vrow * SEQ + (vseg ^ (vrow & 7)) * 8;
        }

        float c_nt[4];
#pragma unroll
        for (int nt = 0; nt < 4; ++nt) c_nt[nt] = slope2 * (float)(nt * 16 + lr);

        const int q0 = qgw * 64 + (wave & 3) * 16;
        short8 qf[4];
#pragma unroll
        for (int cc = 0; cc < 4; ++cc)
            qf[cc] = *(const short8*)&Qb[(size_t)(q0 + lr) * HD + cc * 32 + lg * 8];

        floatx4 po[8] = {};
        float m[4], lsum[4];
#pragma unroll
        for (int r = 0; r < 4; ++r) { m[r] = -3.0e38f; lsum[r] = 0.0f; }

#pragma unroll 1
        for (int t = t1; t >= t0; --t) {
            // stage K(t) and V(t) into the single buffers (reads of t+1's data
            // finished at the previous end barrier)
#pragma unroll
            for (int j = 0; j < 2; ++j) {
                GL16(gK[j] + (size_t)(t << 6) * HD, &sK[0] + lOff[j]);
                GL16(gV[j] + (t << 6), &sV[0] + lOff[j]);
            }
            __syncthreads();   // drain: K(t), V(t) resident block-wide

            const bool active = (t <= qgw) && (t > qgw - W);
            const int kv0 = t << 6;

            if (active) {
                floatx4 sf[4];
                __builtin_amdgcn_s_setprio(1);
#pragma unroll
                for (int nt = 0; nt < 4; ++nt) {
                    floatx4 sacc = {0.f, 0.f, 0.f, 0.f};
#pragma unroll
                    for (int cc = 0; cc < 4; ++cc) {
                        int krow = nt * 16 + lr;
                        short8 kf = *(const short8*)&sK[krow * 128 + (((cc * 4 + lg) ^ (krow & 7)) * 8)];
                        sacc = __builtin_amdgcn_mfma_f32_16x16x32_bf16(qf[cc], kf, sacc, 0, 0, 0);
                    }
                    sf[nt] = sacc;
                }
                __builtin_amdgcn_s_setprio(0);

                const float a2t = slope2 * (float)kv0;
                const bool masked = (t == qgw);
#pragma unroll
                for (int r = 0; r < 4; ++r) {
                    const int qpos = q0 + lg * 4 + r;
                    const int row = lg * 4 + r;
                    float sv[4];
#pragma unroll
                    for (int nt = 0; nt < 4; ++nt)
                        sv[nt] = sf[nt][r] + a2t + c_nt[nt];   // base-2 score
                    if (masked) {
#pragma unroll
                        for (int nt = 0; nt < 4; ++nt) {
                            int kpos = kv0 + nt * 16 + lr;
                            if (kpos > qpos) sv[nt] = -3.0e38f;
                        }
                    }
                    bool over = (sv[0] > m[r]) | (sv[1] > m[r]) | (sv[2] > m[r]) | (sv[3] > m[r]);
                    if (__any(over)) {
                        float mx = fmaxf(fmaxf(sv[0], sv[1]), fmaxf(sv[2], sv[3]));
#pragma unroll
                        for (int off = 1; off < 16; off <<= 1) mx = fmaxf(mx, __shfl_xor(mx, off));
                        float mn = fmaxf(m[r], mx);
                        float rs = exp2f(m[r] - mn);
                        lsum[r] *= rs;
#pragma unroll
                        for (int dt = 0; dt < 8; ++dt) po[dt][r] *= rs;
                        m[r] = mn;
                    }
#pragma unroll
                    for (int nt = 0; nt < 4; ++nt) {
                        float pp = exp2f(sv[nt] - m[r]);
                        lsum[r] += pp;
                        // col nt*16+lr -> block (nt*2+(lr>>3)) ^ (row&7), elem lr&7
                        Plds[wave][row][(((nt * 2 + (lr >> 3)) ^ (row & 7)) << 3) + (lr & 7)] = f2bf(pp);
                    }
                }

                // PV immediately (Plds wave-private; LDS ops in-order per wave)
                short8 pf0 = *(const short8*)&Plds[wave][lr][((lg       ^ (lr & 7)) << 3)];
                short8 pf1 = *(const short8*)&Plds[wave][lr][(((4 + lg) ^ (lr & 7)) << 3)];
                __builtin_amdgcn_s_setprio(1);
#pragma unroll
                for (int dt = 0; dt < 8; ++dt) {
                    int vrow = dt * 16 + lr;
                    short8 vf0 = *(const short8*)&sV[vrow * 64 + (((lg    ) ^ (vrow & 7)) * 8)];
                    short8 vf1 = *(const short8*)&sV[vrow * 64 + (((lg + 4) ^ (vrow & 7)) * 8)];
                    po[dt] = __builtin_amdgcn_mfma_f32_16x16x32_bf16(pf0, vf0, po[dt], 0, 0, 0);
                    po[dt] = __builtin_amdgcn_mfma_f32_16x16x32_bf16(pf1, vf1, po[dt], 0, 0, 0);
                }
                __builtin_amdgcn_s_setprio(0);
            }

            __syncthreads();   // end barrier: all waves done reading sK/sV
        }

        if (!split) {
#pragma unroll
            for (int r = 0; r < 4; ++r) {
                float sum = lsum[r];
#pragma unroll
                for (int off = 1; off < 16; off <<= 1) sum += __shfl_xor(sum, off);
                float inv = 1.0f / sum;
                int row = q0 + lg * 4 + r;
#pragma unroll
                for (int dt = 0; dt < 8; ++dt)
                    Y[((size_t)(b * SEQ + row)) * EMBD + h * HD + dt * 16 + lr] = f2bf(po[dt][r] * inv);
            }
        } else {
            int jslot = b * 48 + (h - 10) * 8 + (p - 8);
            float* pw = part + (size_t)(jslot * 2 + c) * (128 * 130);
#pragma unroll
            for (int r = 0; r < 4; ++r) {
                float sum = lsum[r];
#pragma unroll
                for (int off = 1; off < 16; off <<= 1) sum += __shfl_xor(sum, off);
                int rr = wave * 16 + lg * 4 + r;
#pragma unroll
                for (int dt = 0; dt < 8; ++dt)
                    pw[rr * 130 + dt * 16 + lr] = po[dt][r];
                if (lr == 0) { pw[rr * 130 + 128] = m[r]; pw[rr * 130 + 129] = sum; }
            }
        }
    }
}

// ---------------- combine partial chunks (96 split units x 128 rows) ----------
__global__ void attn_combine(const float* __restrict__ part, short* __restrict__ Y) {
    const int tid = threadIdx.x;
    const int rg  = blockIdx.x * 2 + (tid >> 7);   // 0..12287
    const int col = tid & 127;
    const int j = rg >> 7, rr = rg & 127;
    const int b = j / 48; const int r2 = j % 48;
    const int h = 10 + r2 / 8, p = 8 + r2 % 8;

    const float* p0 = part + ((size_t)(j * 2) * 128 + rr) * 130;
    const float* p1 = p0 + 128 * 130;
    float m0 = p0[128], l0 = p0[129];
    float m1 = p1[128], l1 = p1[129];
    float M = fmaxf(m0, m1);
    float s0 = exp2f(m0 - M), s1 = exp2f(m1 - M);
    float v = (p0[col] * s0 + p1[col] * s1) / (l0 * s0 + l1 * s1);

    const int w = rr >> 4, i2 = rr & 15;
    const int grow = (w < 4 ? (2 * p + 1) : (2 * p)) * 64 + (w & 3) * 16 + i2;
    Y[((size_t)(b * SEQ + grow)) * EMBD + h * HD + col] = f2bf(v);
}

// ---------------- launch ----------------
extern "C" void kernel_launch(void* const* d_in, const int* in_sizes, int n_in,
                              void* d_out, int out_size, void* d_ws, size_t ws_size,
                              hipStream_t stream) {
    const float* x   = (const float*)d_in[0];
    const float* q_w = (const float*)d_in[1];
    const float* k_w = (const float*)d_in[2];
    const float* v_w = (const float*)d_in[3];
    const float* o_w = (const float*)d_in[4];
    float* out = (float*)d_out;

    char* ws = (char*)d_ws;
    short* x_bf  = (short*)(ws);                       // 4096x2048      16.8MB
    short* w_all = (short*)(ws + 16777216);            // 3072x2048      12.6MB
    short* o_wb  = (short*)(ws + 29360128);            // 2048x2048       8.4MB
    short* q_b   = (short*)(ws + 37748736);            // [2,16,2048,128] 16.8MB
    short* k_b   = (short*)(ws + 54525952);            // [2,4,2048,128]  4.2MB
    short* vT_b  = (short*)(ws + 58720256);            // [2,4,128,2048]  4.2MB
    short* y_b   = (short*)(ws + 62914560);            // 4096x2048      16.8MB
    int*   qcnt  = (int*)(ws);                         // pull counter (dead x_bf)
    float* part  = (float*)(ws + 65536);               // partials: 12.8MB, same hole

    cvt_all<<<18432, 256, 0, stream>>>(x, q_w, k_w, v_w, o_w, x_bf, w_all, o_wb);

    gemm_bt<0><<<dim3(NQKV / 128, 4096 / 128), 256, 0, stream>>>(
        x_bf, w_all, nullptr, 4096, NQKV, EMBD, q_b, k_b, vT_b);

    hipMemsetAsync(qcnt, 0, 4, stream);                // after gemm<0>: x_bf dead
    attn_fwd<<<768, 512, 0, stream>>>(q_b, k_b, vT_b, y_b, part, qcnt);
    attn_combine<<<6144, 256, 0, stream>>>(part, y_b);

    gemm_bt<1><<<dim3(EMBD / 128, 4096 / 128), 256, 0, stream>>>(
        y_b, o_wb, out, 4096, EMBD, EMBD, nullptr, nullptr, nullptr);
}

// Round 21
// 193.799 us; speedup vs baseline: 1.9245x; 1.9245x over previous
//
#include <hip/hip_runtime.h>
#include <hip/hip_bf16.h>
#include <math.h>

#define SEQ   2048
#define EMBD  2048
#define NH    16
#define NKV   4
#define HD    128
#define NQKV  3072
#define NUNITS 608        // 512 strip-pair units + 96 second-chunks of split units

typedef __attribute__((ext_vector_type(8))) short short8;
typedef __attribute__((ext_vector_type(4))) short short4v;
typedef __attribute__((ext_vector_type(4))) float floatx4;

static __device__ __forceinline__ short f2bf(float f) {
    union { float f; unsigned u; } cv; cv.f = f;
    unsigned u = cv.u;
    u += 0x7FFF + ((u >> 16) & 1);   // round-to-nearest-even
    return (short)(u >> 16);
}

// async global->LDS, 16B per lane. LDS dest = wave-uniform base + lane*16.
#define GL16(gsrc, ldst)                                                        \
    __builtin_amdgcn_global_load_lds(                                           \
        (const __attribute__((address_space(1))) void*)(gsrc),                  \
        (__attribute__((address_space(3))) void*)(ldst), 16, 0, 0)

// ALiBi window in 64-tiles: truncated mass beyond W is < ~0.2% relative
static __device__ __forceinline__ int alibi_window(float slope2) {
    return (int)ceilf((32.0f / slope2 + 63.0f) * (1.0f / 64.0f));
}

// ---------------- compile-time cost-sorted unit table -------------------------
// Unit order is a pure function of shape; only scheduling (not correctness)
// depends on it: kernel derives its own bounds from (c,b,h,p). W_TAB mirrors
// alibi_window(slope2(h)) for h=0..15.
struct QTab { int v[NUNITS]; };
static constexpr int W_TAB[16] = {2,2,2,3,3,4,5,7,9,13,17,24,33,46,64,90};
static constexpr QTab make_qtab() {
    QTab t{};
    int cost[NUNITS] = {}, enc[NUNITS] = {};
    for (int i = 0; i < NUNITS; ++i) {
        int b, h, p, c;
        if (i < 512) { b = i >> 8; h = (i >> 4) & 15; p = i & 15; c = 0; }
        else { int j = i - 512; b = j / 48; int r2 = j % 48; h = 10 + r2 / 8; p = 8 + r2 % 8; c = 1; }
        int W = W_TAB[h];
        int L = (W + 1 < 2 * p + 2) ? (W + 1) : (2 * p + 2);
        int n0 = (L + 1) >> 1;
        bool split = (h >= 10) && (p >= 8);
        cost[i] = split ? (c == 0 ? n0 : L - n0) : L;
        enc[i] = (c << 9) | (b << 8) | (h << 4) | p;
    }
    int idx = 0;
    for (int cval = 32; cval >= 1; --cval)          // counting sort, cost desc
        for (int i = NUNITS - 1; i >= 0; --i)       // larger i first (matches old key)
            if (cost[i] == cval) t.v[idx++] = enc[i];
    return t;
}
static __constant__ QTab d_qt = make_qtab();

// ---------------- fused fp32 -> bf16 convert (all 5 tensors, one launch) ------
__global__ void cvt_all(const float* __restrict__ x,  const float* __restrict__ qw,
                        const float* __restrict__ kw, const float* __restrict__ vw,
                        const float* __restrict__ ow,
                        short* __restrict__ xb, short* __restrict__ wall,
                        short* __restrict__ owb) {
    int i = blockIdx.x * blockDim.x + threadIdx.x;   // quad index, < 4718592
    const float* src; short* dst; int off;
    if (i < 2097152)      { src = x;  dst = xb;             off = i; }
    else if (i < 3145728) { src = qw; dst = wall;           off = i - 2097152; }
    else if (i < 3407872) { src = kw; dst = wall + 4194304; off = i - 3145728; }
    else if (i < 3670016) { src = vw; dst = wall + 5242880; off = i - 3407872; }
    else                  { src = ow; dst = owb;            off = i - 3670016; }
    float4 v = ((const float4*)src)[off];
    float a[4] = {v.x, v.y, v.z, v.w};
    short4v o;
#pragma unroll
    for (int j = 0; j < 4; ++j) {
        float f = a[j];
        f = isnan(f) ? 0.0f : fminf(fmaxf(f, -10000.0f), 10000.0f);
        o[j] = f2bf(f);
    }
    ((short4v*)dst)[off] = o;
}

// ---------------- bf16 GEMM: 128x128 tile, BK=64, swizzled LDS (R15) ----------
// global_load_lds staging with pre-XORed source (seg^(row&7) on 16B chunks);
// fragment ds_read_b128 XORs the same way -> 2-way (free) bank access.
// Single-buffered: cross-block TLP (4 blocks/CU at 32KB LDS) hides the drain.
// MODE 0: scatter epilogue -> Q (pre-scaled by scale*log2e), K, VT (bf16)
// MODE 1: plain fp32 store
template<int MODE>
__global__ __launch_bounds__(256) void gemm_bt(
    const short* __restrict__ A, const short* __restrict__ W,
    float* __restrict__ Cout, int M, int N, int K,
    short* __restrict__ qb, short* __restrict__ kb, short* __restrict__ vb)
{
    __shared__ __align__(16) short sA[128 * 64];
    __shared__ __align__(16) short sB[128 * 64];

    const int tid  = threadIdx.x;
    const int lane = tid & 63;
    const int wv   = tid >> 6;
    const int wr   = wv >> 1, wc = wv & 1;       // 2x2 wave grid, 64x64 each
    const int lr   = lane & 15, lg = lane >> 4;
    const int bn   = blockIdx.x, bm = blockIdx.y;

    // staging: 1024 chunks(16B) per matrix; wave w covers [w*256, w*256+256)
    const short* gA[4]; const short* gB[4];
    short* lA[4]; short* lB[4];
#pragma unroll
    for (int s = 0; s < 4; ++s) {
        int ck  = wv * 256 + s * 64 + lane;
        int row = ck >> 3, seg = ck & 7;         // 8x16B chunks per 64-short row
        int segSw = seg ^ (row & 7);             // pre-swizzled source column
        gA[s] = A + (size_t)(bm * 128 + row) * K + segSw * 8;
        gB[s] = W + (size_t)(bn * 128 + row) * K + segSw * 8;
        lA[s] = &sA[(wv * 256 + s * 64) * 8];    // linear dest
        lB[s] = &sB[(wv * 256 + s * 64) * 8];
    }

    floatx4 acc[4][4] = {};
    const int nkt = K / 64;
    for (int kt = 0; kt < nkt; ++kt) {
#pragma unroll
        for (int s = 0; s < 4; ++s) {
            GL16(gA[s] + kt * 64, lA[s]);
            GL16(gB[s] + kt * 64, lB[s]);
        }
        __syncthreads();

#pragma unroll
        for (int ks = 0; ks < 2; ++ks) {
            short8 af[4], bfr[4];
#pragma unroll
            for (int i = 0; i < 4; ++i) {
                int ra = wr * 64 + i * 16 + lr;
                int rb = wc * 64 + i * 16 + lr;
                af[i]  = *(const short8*)&sA[ra * 64 + (((ks * 4 + lg) ^ (ra & 7)) * 8)];
                bfr[i] = *(const short8*)&sB[rb * 64 + (((ks * 4 + lg) ^ (rb & 7)) * 8)];
            }
#pragma unroll
            for (int i = 0; i < 4; ++i)
#pragma unroll
                for (int j = 0; j < 4; ++j)
                    acc[i][j] = __builtin_amdgcn_mfma_f32_16x16x32_bf16(af[i], bfr[j], acc[i][j], 0, 0, 0);
        }
        __syncthreads();
    }

    const float QSCALE = 0.08838834764831845f * 1.44269504f;  // scale * log2e
#pragma unroll
    for (int i = 0; i < 4; ++i)
#pragma unroll
        for (int j = 0; j < 4; ++j)
#pragma unroll
            for (int r = 0; r < 4; ++r) {
                int gm = bm * 128 + wr * 64 + i * 16 + lg * 4 + r;
                int gn = bn * 128 + wc * 64 + j * 16 + lr;
                float v = acc[i][j][r];
                if (MODE == 0) {
                    int b = gm >> 11, t = gm & (SEQ - 1);
                    if (gn < 2048) {
                        int h = gn >> 7, d = gn & 127;
                        qb[(((size_t)(b * NH + h)) * SEQ + t) * HD + d] = f2bf(v * QSCALE);
                    } else if (gn < 2560) {
                        int hk = (gn - 2048) >> 7, d = gn & 127;
                        kb[(((size_t)(b * NKV + hk)) * SEQ + t) * HD + d] = f2bf(v);
                    } else {
                        int hv = (gn - 2560) >> 7, d = gn & 127;
                        vb[(((size_t)(b * NKV + hv)) * HD + d) * SEQ + t] = f2bf(v);
                    }
                } else {
                    Cout[(size_t)gm * N + gn] = v;
                }
            }
}

// ---------------- flash attention: persistent queue + split heavy units -------
// (R19 verbatim — best measured state.) 512 persistent blocks (8 waves,
// 67.7KB LDS -> 2/CU, all resident). Blocks pull units from the compile-time
// cost-sorted __constant__ table via a global counter (zeroed by
// hipMemsetAsync): online LPT, max grain 17 tiles. Heavy units pre-split into
// 2 KV chunks (fp32 partials -> attn_combine). Tile body: dbuf K,
// single-buffer V, 2 barriers, setprio on MFMA clusters.
__global__ __launch_bounds__(512, 4) void attn_fwd(
    const short* __restrict__ Q, const short* __restrict__ Kg,
    const short* __restrict__ VT, short* __restrict__ Y,
    float* __restrict__ part, int* __restrict__ qcnt)
{
    __shared__ __align__(16) short sK[2][64 * 128];   // 32 KB, swizzled chunks
    __shared__ __align__(16) short sV[128 * 64];      // 16 KB, swizzled chunks
    __shared__ short Plds[8][16][72];                 // 18 KB
    __shared__ int s_unit;

    const int tid  = threadIdx.x;
    const int wave = tid >> 6, lane = tid & 63;
    const int lr = lane & 15, lg = lane >> 4;

    int lOff[2];
#pragma unroll
    for (int j = 0; j < 2; ++j)
        lOff[j] = (wave * 128 + j * 64 + lane) * 8;   // lane-linear, 16B chunks

    for (;;) {
        if (tid == 0) {
            int r = atomicAdd(qcnt, 1);
            s_unit = (r < NUNITS) ? d_qt.v[r] : -1;
        }
        __syncthreads();
        const int enc = s_unit;
        __syncthreads();
        if (enc < 0) break;

        const int c = (enc >> 9) & 1, b = (enc >> 8) & 1;
        const int h = (enc >> 4) & 15, p = enc & 15;
        const int hkv = h >> 2;               // repeat_interleave: head h -> kv h/4
        const int qgw = 2 * p + (wave < 4 ? 1 : 0);   // this wave's strip

        const short* Qb = Q  +  ((size_t)(b * NH  + h  )) * SEQ * HD;
        const short* Kp = Kg +  ((size_t)(b * NKV + hkv)) * SEQ * HD;
        const short* Vp = VT +  ((size_t)(b * NKV + hkv)) * HD * SEQ;

        const float slope2 = exp2f(-0.5f * (float)(h + 1)) * 1.44269504f;
        const int W = alibi_window(slope2);
        const int thi = 2 * p + 1;
        const int L = min(W + 1, 2 * p + 2);
        const bool split = (h >= 10) && (p >= 8);
        const int n0 = (L + 1) >> 1;
        int t1, t0;
        if (!split)      { t1 = thi;      t0 = thi - L + 1; }
        else if (c == 0) { t1 = thi;      t0 = thi - n0 + 1; }
        else             { t1 = thi - n0; t0 = thi - L + 1; }

        const short* gK[2]; const short* gV[2];
#pragma unroll
        for (int j = 0; j < 2; ++j) {
            int ck = wave * 128 + j * 64 + lane;
            int krow = ck >> 4, kseg = ck & 15;
            gK[j] = Kp + (size_t)krow * HD + (kseg ^ (krow & 7)) * 8;   // pre-swz src
            int vrow = ck >> 3, vseg = ck & 7;
            gV[j] = Vp + (size_t)vrow * SEQ + (vseg ^ (vrow & 7)) * 8;
        }

        float c_nt[4];
#pragma unroll
        for (int nt = 0; nt < 4; ++nt) c_nt[nt] = slope2 * (float)(nt * 16 + lr);

        const int q0 = qgw * 64 + (wave & 3) * 16;
        short8 qf[4];
#pragma unroll
        for (int cc = 0; cc < 4; ++cc)
            qf[cc] = *(const short8*)&Qb[(size_t)(q0 + lr) * HD + cc * 32 + lg * 8];

        floatx4 po[8] = {};
        float m[4], lsum[4];
#pragma unroll
        for (int r = 0; r < 4; ++r) { m[r] = -3.0e38f; lsum[r] = 0.0f; }

        int cur = 0;
        // prologue: stage K(t1)
#pragma unroll
        for (int j = 0; j < 2; ++j)
            GL16(gK[j] + (size_t)(t1 << 6) * HD, &sK[0][0] + lOff[j]);
        __syncthreads();

#pragma unroll 1
        for (int t = t1; t >= t0; --t) {
            // stage V(t); prefetch K(t-1) into other K buffer
#pragma unroll
            for (int j = 0; j < 2; ++j)
                GL16(gV[j] + (t << 6), &sV[0] + lOff[j]);
            if (t > t0) {
#pragma unroll
                for (int j = 0; j < 2; ++j)
                    GL16(gK[j] + (size_t)((t - 1) << 6) * HD, &sK[cur ^ 1][0] + lOff[j]);
            }

            const bool active = (t <= qgw) && (t > qgw - W);
            const int kv0 = t << 6;

            if (active) {
                const short* kr = &sK[cur][0];
                floatx4 sf[4];
                __builtin_amdgcn_s_setprio(1);
#pragma unroll
                for (int nt = 0; nt < 4; ++nt) {
                    floatx4 sacc = {0.f, 0.f, 0.f, 0.f};
#pragma unroll
                    for (int cc = 0; cc < 4; ++cc) {
                        int krow = nt * 16 + lr;
                        short8 kf = *(const short8*)&kr[krow * 128 + (((cc * 4 + lg) ^ (krow & 7)) * 8)];
                        sacc = __builtin_amdgcn_mfma_f32_16x16x32_bf16(qf[cc], kf, sacc, 0, 0, 0);
                    }
                    sf[nt] = sacc;
                }
                __builtin_amdgcn_s_setprio(0);

                const float a2t = slope2 * (float)kv0;
                const bool masked = (t == qgw);
#pragma unroll
                for (int r = 0; r < 4; ++r) {
                    const int qpos = q0 + lg * 4 + r;
                    float sv[4];
#pragma unroll
                    for (int nt = 0; nt < 4; ++nt)
                        sv[nt] = sf[nt][r] + a2t + c_nt[nt];   // base-2 score
                    if (masked) {
#pragma unroll
                        for (int nt = 0; nt < 4; ++nt) {
                            int kpos = kv0 + nt * 16 + lr;
                            if (kpos > qpos) sv[nt] = -3.0e38f;
                        }
                    }
                    bool over = (sv[0] > m[r]) | (sv[1] > m[r]) | (sv[2] > m[r]) | (sv[3] > m[r]);
                    if (__any(over)) {
                        float mx = fmaxf(fmaxf(sv[0], sv[1]), fmaxf(sv[2], sv[3]));
#pragma unroll
                        for (int off = 1; off < 16; off <<= 1) mx = fmaxf(mx, __shfl_xor(mx, off));
                        float mn = fmaxf(m[r], mx);
                        float rs = exp2f(m[r] - mn);
                        lsum[r] *= rs;
#pragma unroll
                        for (int dt = 0; dt < 8; ++dt) po[dt][r] *= rs;
                        m[r] = mn;
                    }
#pragma unroll
                    for (int nt = 0; nt < 4; ++nt) {
                        float pp = exp2f(sv[nt] - m[r]);
                        lsum[r] += pp;
                        Plds[wave][lg * 4 + r][nt * 16 + lr] = f2bf(pp);
                    }
                }
            }

            __syncthreads();   // barrier 1: V(t) (and K(t-1)) staged

            if (active) {
                short8 pf0 = *(const short8*)&Plds[wave][lr][lg * 8];
                short8 pf1 = *(const short8*)&Plds[wave][lr][32 + lg * 8];
                __builtin_amdgcn_s_setprio(1);
#pragma unroll
                for (int dt = 0; dt < 8; ++dt) {
                    int vrow = dt * 16 + lr;
                    short8 vf0 = *(const short8*)&sV[vrow * 64 + (((lg    ) ^ (vrow & 7)) * 8)];
                    short8 vf1 = *(const short8*)&sV[vrow * 64 + (((lg + 4) ^ (vrow & 7)) * 8)];
                    po[dt] = __builtin_amdgcn_mfma_f32_16x16x32_bf16(pf0, vf0, po[dt], 0, 0, 0);
                    po[dt] = __builtin_amdgcn_mfma_f32_16x16x32_bf16(pf1, vf1, po[dt], 0, 0, 0);
                }
                __builtin_amdgcn_s_setprio(0);
            }

            __syncthreads();   // barrier 2: sV and sK[cur] free for next iteration
            cur ^= 1;
        }

        if (!split) {
#pragma unroll
            for (int r = 0; r < 4; ++r) {
                float sum = lsum[r];
#pragma unroll
                for (int off = 1; off < 16; off <<= 1) sum += __shfl_xor(sum, off);
                float inv = 1.0f / sum;
                int row = q0 + lg * 4 + r;
#pragma unroll
                for (int dt = 0; dt < 8; ++dt)
                    Y[((size_t)(b * SEQ + row)) * EMBD + h * HD + dt * 16 + lr] = f2bf(po[dt][r] * inv);
            }
        } else {
            int jslot = b * 48 + (h - 10) * 8 + (p - 8);
            float* pw = part + (size_t)(jslot * 2 + c) * (128 * 130);
#pragma unroll
            for (int r = 0; r < 4; ++r) {
                float sum = lsum[r];
#pragma unroll
                for (int off = 1; off < 16; off <<= 1) sum += __shfl_xor(sum, off);
                int rr = wave * 16 + lg * 4 + r;
#pragma unroll
                for (int dt = 0; dt < 8; ++dt)
                    pw[rr * 130 + dt * 16 + lr] = po[dt][r];
                if (lr == 0) { pw[rr * 130 + 128] = m[r]; pw[rr * 130 + 129] = sum; }
            }
        }
    }
}

// ---------------- combine partial chunks (96 split units x 128 rows) ----------
__global__ void attn_combine(const float* __restrict__ part, short* __restrict__ Y) {
    const int tid = threadIdx.x;
    const int rg  = blockIdx.x * 2 + (tid >> 7);   // 0..12287
    const int col = tid & 127;
    const int j = rg >> 7, rr = rg & 127;
    const int b = j / 48; const int r2 = j % 48;
    const int h = 10 + r2 / 8, p = 8 + r2 % 8;

    const float* p0 = part + ((size_t)(j * 2) * 128 + rr) * 130;
    const float* p1 = p0 + 128 * 130;
    float m0 = p0[128], l0 = p0[129];
    float m1 = p1[128], l1 = p1[129];
    float M = fmaxf(m0, m1);
    float s0 = exp2f(m0 - M), s1 = exp2f(m1 - M);
    float v = (p0[col] * s0 + p1[col] * s1) / (l0 * s0 + l1 * s1);

    const int w = rr >> 4, i2 = rr & 15;
    const int grow = (w < 4 ? (2 * p + 1) : (2 * p)) * 64 + (w & 3) * 16 + i2;
    Y[((size_t)(b * SEQ + grow)) * EMBD + h * HD + col] = f2bf(v);
}

// ---------------- launch ----------------
extern "C" void kernel_launch(void* const* d_in, const int* in_sizes, int n_in,
                              void* d_out, int out_size, void* d_ws, size_t ws_size,
                              hipStream_t stream) {
    const float* x   = (const float*)d_in[0];
    const float* q_w = (const float*)d_in[1];
    const float* k_w = (const float*)d_in[2];
    const float* v_w = (const float*)d_in[3];
    const float* o_w = (const float*)d_in[4];
    float* out = (float*)d_out;

    char* ws = (char*)d_ws;
    short* x_bf  = (short*)(ws);                       // 4096x2048      16.8MB
    short* w_all = (short*)(ws + 16777216);            // 3072x2048      12.6MB
    short* o_wb  = (short*)(ws + 29360128);            // 2048x2048       8.4MB
    short* q_b   = (short*)(ws + 37748736);            // [2,16,2048,128] 16.8MB
    short* k_b   = (short*)(ws + 54525952);            // [2,4,2048,128]  4.2MB
    short* vT_b  = (short*)(ws + 58720256);            // [2,4,128,2048]  4.2MB
    short* y_b   = (short*)(ws + 62914560);            // 4096x2048      16.8MB
    int*   qcnt  = (int*)(ws);                         // pull counter (dead x_bf)
    float* part  = (float*)(ws + 65536);               // partials: 12.8MB, same hole

    cvt_all<<<18432, 256, 0, stream>>>(x, q_w, k_w, v_w, o_w, x_bf, w_all, o_wb);

    gemm_bt<0><<<dim3(NQKV / 128, 4096 / 128), 256, 0, stream>>>(
        x_bf, w_all, nullptr, 4096, NQKV, EMBD, q_b, k_b, vT_b);

    hipMemsetAsync(qcnt, 0, 4, stream);                // after gemm<0>: x_bf dead
    attn_fwd<<<512, 512, 0, stream>>>(q_b, k_b, vT_b, y_b, part, qcnt);
    attn_combine<<<6144, 256, 0, stream>>>(part, y_b);

    gemm_bt<1><<<dim3(EMBD / 128, 4096 / 128), 256, 0, stream>>>(
        y_b, o_wb, out, 4096, EMBD, EMBD, nullptr, nullptr, nullptr);
}